// Round 15
// baseline (176.739 us; speedup 1.0000x reference)
//
#include <hip/hip_runtime.h>
#include <hip/hip_bf16.h>
#include <math.h>

#define NB   16
#define CIN  64
#define LEN  8192
#define LP2  8195
#define COUT 64
#define MSZ  192
#define REP  8        // diagnostic replication factor (idempotent reps in one dispatch)

typedef float    f32x4 __attribute__((ext_vector_type(4)));
typedef _Float16 f16x8 __attribute__((ext_vector_type(8)));
typedef _Float16 f16x2 __attribute__((ext_vector_type(2)));

static __device__ inline unsigned int pkrtz(float lo, float hi) {
    return __builtin_bit_cast(unsigned int, __builtin_amdgcn_cvt_pkrtz(lo, hi));
}

// ---------------- Kernel P4-mega: R13 prep4, grid replicated REP x (diagnostic) ----------------
__global__ __launch_bounds__(256) void prep4_kernel(
    const float* __restrict__ x, const float* __restrict__ w_off,
    const float* __restrict__ b_off, const float* __restrict__ w,
    float* __restrict__ gbuf, unsigned int* __restrict__ xt32,
    unsigned short* __restrict__ wtf)
{
    int bid = blockIdx.x;
    int tid = threadIdx.x;

    if (bid >= REP * NB * 128) {
        int b = bid - REP * NB * 128;    // 0..23
        int ot = b / 6, ks = b - ot * 6;
        #pragma unroll
        for (int h = 0; h < 2; ++h) {
            int t2 = tid + h * 256;
            int lq = t2 >> 3, s = t2 & 7;
            int o = ot * 16 + (lq & 15);
            int m = ks * 32 + (lq >> 4) * 8 + s;
            _Float16 hv = (_Float16)w[o * MSZ + m];
            wtf[b * 512 + t2] = __builtin_bit_cast(unsigned short, hv);
        }
        return;
    }

    __shared__ float ps[4][3][64];
    __shared__ unsigned int bt[64 * 33];

    int inner = bid & (NB * 128 - 1);    // rep = bid >> 11 (all reps identical)
    int lane = tid & 63;
    int wid  = __builtin_amdgcn_readfirstlane(tid >> 6);
    int xcd = inner & 7;
    int tt  = inner >> 3;
    int n   = (xcd << 1) | (tt >> 7);
    int t   = tt & 127;
    int l0 = t << 6;
    int l  = l0 + lane;
    const float* xn = x + (size_t)n * (CIN * LEN);
    bool okm = (l >= 1);
    bool okp = (l < LEN - 1);

    float a0 = 0.f, a1 = 0.f, a2 = 0.f;
    unsigned int pk[8];

    #pragma unroll
    for (int ci = 0; ci < 16; ci += 2) {
        int c0 = (wid << 4) | ci;
        const float* xc0 = xn + (size_t)c0 * LEN;
        const float* xc1 = xc0 + LEN;
        float xm0 = okm ? xc0[l - 1] : 0.f;
        float x00 = xc0[l];
        float xp0 = okp ? xc0[l + 1] : 0.f;
        float xm1 = okm ? xc1[l - 1] : 0.f;
        float x01 = xc1[l];
        float xp1 = okp ? xc1[l + 1] : 0.f;
        const float* wa = w_off + (size_t)c0 * 3;
        const float* wb = wa + 384;
        const float* wc = wa + 768;
        a0 = fmaf(wa[0], xm0, a0); a0 = fmaf(wa[1], x00, a0); a0 = fmaf(wa[2], xp0, a0);
        a0 = fmaf(wa[3], xm1, a0); a0 = fmaf(wa[4], x01, a0); a0 = fmaf(wa[5], xp1, a0);
        a1 = fmaf(wb[0], xm0, a1); a1 = fmaf(wb[1], x00, a1); a1 = fmaf(wb[2], xp0, a1);
        a1 = fmaf(wb[3], xm1, a1); a1 = fmaf(wb[4], x01, a1); a1 = fmaf(wb[5], xp1, a1);
        a2 = fmaf(wc[0], xm0, a2); a2 = fmaf(wc[1], x00, a2); a2 = fmaf(wc[2], xp0, a2);
        a2 = fmaf(wc[3], xm1, a2); a2 = fmaf(wc[4], x01, a2); a2 = fmaf(wc[5], xp1, a2);
        pk[ci >> 1] = pkrtz(x00, x01);
    }

    ps[wid][0][lane] = a0;
    ps[wid][1][lane] = a1;
    ps[wid][2][lane] = a2;
    #pragma unroll
    for (int j = 0; j < 8; ++j)
        bt[lane * 33 + (wid << 3) + j] = pk[j];
    __syncthreads();

    if (tid < 192) {
        int k = tid >> 6, ll = tid & 63;
        float s = b_off[2 * k];
        #pragma unroll
        for (int w4 = 0; w4 < 4; ++w4) s += ps[w4][k][ll];
        float g = fminf(fmaxf((float)(l0 + ll + 1) + s, 0.f), 8193.f);
        gbuf[((size_t)n * LEN + l0 + ll) * 3 + k] = g;
    }

    {
        int row = tid >> 2, grp = tid & 3;
        const unsigned int* src = &bt[row * 33 + (grp << 3)];
        uint4 u0, u1;
        u0.x = src[0]; u0.y = src[1]; u0.z = src[2]; u0.w = src[3];
        u1.x = src[4]; u1.y = src[5]; u1.z = src[6]; u1.w = src[7];
        size_t base = ((size_t)n * LP2 + 1 + l0 + row) * 32 + (grp << 3);
        *(uint4*)&xt32[base]     = u0;
        *(uint4*)&xt32[base + 4] = u1;
    }
    if (t == 0   && tid < 32) xt32[((size_t)n * LP2) * 32 + tid] = 0u;
    if (t == 127 && tid < 64) xt32[((size_t)n * LP2 + 8193 + (tid >> 5)) * 32 + (tid & 31)] = 0u;
}

// ---------------- Kernel D8-mega: R13 dconv8, grid replicated REP x (diagnostic) ----------------
__global__ __launch_bounds__(256) void dconv8_kernel(
    const unsigned short* __restrict__ xt16, const unsigned short* __restrict__ wtf,
    const float* __restrict__ bias, const float* __restrict__ gbuf,
    float* __restrict__ out)
{
    __shared__ unsigned short Bl[MSZ * 64];
    __shared__ __align__(16) int2 meta[MSZ];
    int tid = threadIdx.x;

    int wg  = blockIdx.x & (NB * 128 - 1);   // rep = blockIdx.x >> 11 (identical work)
    int xcd = wg & 7;
    int tt  = wg >> 3;
    int n   = (xcd << 1) | (tt >> 7);
    int p   = tt & 127;

    if (tid < MSZ) {
        int k = tid >> 6, r = tid & 63;
        int l = (r << 7) | p;
        float g  = gbuf[((size_t)n * LEN + l) * 3 + k];
        float fl = floorf(g);
        meta[tid] = make_int2((int)fl, __float_as_int(g - fl));
    }
    __syncthreads();

    const unsigned short* xb = xt16 + (size_t)n * LP2 * 64;

    #pragma unroll
    for (int j = 0; j < 6; ++j) {
        int task = tid + (j << 8);
        int m  = task >> 3;
        int ch = task & 7;
        int2 mv = meta[m];
        float a = __int_as_float(mv.y);
        _Float16 ah = (_Float16)a;
        f16x2 a2; a2[0] = ah; a2[1] = ah;
        const unsigned short* rl = xb + ((size_t)(unsigned)mv.x << 6) + (ch << 3);
        uint4 vl4 = *(const uint4*)rl;
        uint4 vr4 = *(const uint4*)(rl + 64);
        const f16x2* vlh = (const f16x2*)&vl4;
        const f16x2* vrh = (const f16x2*)&vr4;
        uint4 ov;
        unsigned int* ovp = (unsigned int*)&ov;
        #pragma unroll
        for (int q = 0; q < 4; ++q) {
            f16x2 r = vlh[q] + a2 * (vrh[q] - vlh[q]);
            ovp[q] = __builtin_bit_cast(unsigned int, r);
        }
        int dst = (m << 6) + ((ch << 3) ^ (((m >> 3) & 3) << 4));
        *(uint4*)&Bl[dst] = ov;
    }
    __syncthreads();

    int lane = tid & 63;
    int ct   = tid >> 6;
    int g4   = lane >> 4;
    int c    = (ct << 4) | (lane & 15);

    f32x4 acc[4] = {};

    #pragma unroll
    for (int ks = 0; ks < 6; ++ks) {
        int mb = ks * 32 + (g4 << 3);
        int cx = c ^ ((((unsigned)(mb >> 3)) & 3) << 4);
        f16x8 afrag;
        #pragma unroll
        for (int s = 0; s < 8; ++s)
            afrag[s] = __builtin_bit_cast(_Float16, Bl[((mb + s) << 6) + cx]);

        #pragma unroll
        for (int ot = 0; ot < 4; ++ot) {
            f16x8 bfrag = *(const f16x8*)(wtf + ((size_t)(((ot * 6 + ks) << 6) + lane) << 3));
            acc[ot] = __builtin_amdgcn_mfma_f32_16x16x32_f16(afrag, bfrag, acc[ot], 0, 0, 0);
        }
    }

    int q0 = (p << 6) + ct * 16 + g4 * 4;
    #pragma unroll
    for (int ot = 0; ot < 4; ++ot) {
        int o = ot * 16 + (lane & 15);
        float bb = bias[o];
        float4 r4;
        r4.x = acc[ot][0] + bb;
        r4.y = acc[ot][1] + bb;
        r4.z = acc[ot][2] + bb;
        r4.w = acc[ot][3] + bb;
        *(float4*)&out[((size_t)n * COUT + o) * LEN + q0] = r4;
    }
}

extern "C" void kernel_launch(void* const* d_in, const int* in_sizes, int n_in,
                              void* d_out, int out_size, void* d_ws, size_t ws_size,
                              hipStream_t stream) {
    const float* x     = (const float*)d_in[0];
    const float* w_off = (const float*)d_in[1];
    const float* b_off = (const float*)d_in[2];
    const float* w     = (const float*)d_in[3];
    const float* b     = (const float*)d_in[4];
    float* out = (float*)d_out;

    const size_t GBUF_B = (size_t)NB * LEN * 3 * sizeof(float);
    const size_t WTF_B  = (size_t)MSZ * COUT * sizeof(short);
    float*          gbuf = (float*)d_ws;
    unsigned short* wtf  = (unsigned short*)((char*)d_ws + GBUF_B);
    unsigned int*   xt32 = (unsigned int*)((char*)d_ws + GBUF_B + WTF_B);
    unsigned short* xt16 = (unsigned short*)xt32;

    // DIAGNOSTIC ROUND: each kernel's grid replicated REP=8x inside ONE dispatch
    // (idempotent -> identical output), so both dispatches exceed the 40us harness
    // fills and appear in the rocprof top-5 WITH counters.
    prep4_kernel<<<REP * NB * 128 + 24, 256, 0, stream>>>(x, w_off, b_off, w, gbuf, xt32, wtf);
    dconv8_kernel<<<REP * NB * 128, 256, 0, stream>>>(xt16, wtf, b, gbuf, out);
}

// Round 16
// 33.541 us; speedup vs baseline: 5.2694x; 5.2694x over previous
//
#include <hip/hip_runtime.h>
#include <hip/hip_bf16.h>
#include <math.h>

#define NB   16
#define CIN  64
#define LEN  8192
#define LP2  8195     // rows: 0 = left pad(0), 1..8192 = x, 8193/8194 = right pad(0)
#define COUT 64
#define MSZ  192

typedef float    f32x4  __attribute__((ext_vector_type(4)));
typedef float    f32x4u __attribute__((ext_vector_type(4), aligned(4)));   // 4B-aligned float4
typedef _Float16 f16x8  __attribute__((ext_vector_type(8)));
typedef _Float16 f16x2  __attribute__((ext_vector_type(2)));

static __device__ inline unsigned int pkrtz(float lo, float hi) {
    return __builtin_bit_cast(unsigned int, __builtin_amdgcn_cvt_pkrtz(lo, hi)); // low16=lo, high16=hi
}

// ---------------- Kernel P5: prep4 + float4 tap loads (16 VMEM/thread vs 50) ----------------
__global__ __launch_bounds__(256) void prep5_kernel(
    const float* __restrict__ x, const float* __restrict__ w_off,
    const float* __restrict__ b_off, const float* __restrict__ w,
    float* __restrict__ gbuf, unsigned int* __restrict__ xt32,
    unsigned short* __restrict__ wtf)
{
    int bid = blockIdx.x;
    int tid = threadIdx.x;

    if (bid >= NB * 128) {
        // ---- wfrag: b = ot*6 + ks ----
        int b = bid - NB * 128;          // 0..23
        int ot = b / 6, ks = b - ot * 6;
        #pragma unroll
        for (int h = 0; h < 2; ++h) {
            int t2 = tid + h * 256;
            int lq = t2 >> 3, s = t2 & 7;
            int o = ot * 16 + (lq & 15);
            int m = ks * 32 + (lq >> 4) * 8 + s;
            _Float16 hv = (_Float16)w[o * MSZ + m];
            wtf[b * 512 + t2] = __builtin_bit_cast(unsigned short, hv);
        }
        return;
    }

    __shared__ float ps[4][3][64];
    __shared__ unsigned int bt[64 * 33];

    int lane = tid & 63;
    int wid  = __builtin_amdgcn_readfirstlane(tid >> 6);
    // XCD-aligned mapping: same bijective swizzle as dconv
    int xcd = bid & 7;
    int tt  = bid >> 3;               // 0..255
    int n   = (xcd << 1) | (tt >> 7);
    int t   = tt & 127;
    int l0 = t << 6;
    int l  = l0 + lane;
    const float* xn = x + (size_t)n * (CIN * LEN);

    float a0 = 0.f, a1 = 0.f, a2 = 0.f;
    unsigned int pk[8];

    if (t != 0 && t != 127) {
        // fast path: one unaligned float4 per channel covers taps [l-1, l, l+1]
        #pragma unroll
        for (int ci = 0; ci < 16; ci += 2) {
            int c0 = (wid << 4) | ci;
            const float* xc0 = xn + (size_t)c0 * LEN;
            const float* xc1 = xc0 + LEN;
            f32x4u v0 = *(const f32x4u*)&xc0[l - 1];
            f32x4u v1 = *(const f32x4u*)&xc1[l - 1];
            const float* wa = w_off + (size_t)c0 * 3;
            const float* wb = wa + 384;
            const float* wc = wa + 768;
            a0 = fmaf(wa[0], v0.x, a0); a0 = fmaf(wa[1], v0.y, a0); a0 = fmaf(wa[2], v0.z, a0);
            a0 = fmaf(wa[3], v1.x, a0); a0 = fmaf(wa[4], v1.y, a0); a0 = fmaf(wa[5], v1.z, a0);
            a1 = fmaf(wb[0], v0.x, a1); a1 = fmaf(wb[1], v0.y, a1); a1 = fmaf(wb[2], v0.z, a1);
            a1 = fmaf(wb[3], v1.x, a1); a1 = fmaf(wb[4], v1.y, a1); a1 = fmaf(wb[5], v1.z, a1);
            a2 = fmaf(wc[0], v0.x, a2); a2 = fmaf(wc[1], v0.y, a2); a2 = fmaf(wc[2], v0.z, a2);
            a2 = fmaf(wc[3], v1.x, a2); a2 = fmaf(wc[4], v1.y, a2); a2 = fmaf(wc[5], v1.z, a2);
            pk[ci >> 1] = pkrtz(v0.y, v1.y);
        }
    } else {
        // boundary blocks: scalar loads + edge selects (original prep4 path)
        bool okm = (l >= 1);
        bool okp = (l < LEN - 1);
        #pragma unroll
        for (int ci = 0; ci < 16; ci += 2) {
            int c0 = (wid << 4) | ci;
            const float* xc0 = xn + (size_t)c0 * LEN;
            const float* xc1 = xc0 + LEN;
            float xm0 = okm ? xc0[l - 1] : 0.f;
            float x00 = xc0[l];
            float xp0 = okp ? xc0[l + 1] : 0.f;
            float xm1 = okm ? xc1[l - 1] : 0.f;
            float x01 = xc1[l];
            float xp1 = okp ? xc1[l + 1] : 0.f;
            const float* wa = w_off + (size_t)c0 * 3;
            const float* wb = wa + 384;
            const float* wc = wa + 768;
            a0 = fmaf(wa[0], xm0, a0); a0 = fmaf(wa[1], x00, a0); a0 = fmaf(wa[2], xp0, a0);
            a0 = fmaf(wa[3], xm1, a0); a0 = fmaf(wa[4], x01, a0); a0 = fmaf(wa[5], xp1, a0);
            a1 = fmaf(wb[0], xm0, a1); a1 = fmaf(wb[1], x00, a1); a1 = fmaf(wb[2], xp0, a1);
            a1 = fmaf(wb[3], xm1, a1); a1 = fmaf(wb[4], x01, a1); a1 = fmaf(wb[5], xp1, a1);
            a2 = fmaf(wc[0], xm0, a2); a2 = fmaf(wc[1], x00, a2); a2 = fmaf(wc[2], xp0, a2);
            a2 = fmaf(wc[3], xm1, a2); a2 = fmaf(wc[4], x01, a2); a2 = fmaf(wc[5], xp1, a2);
            pk[ci >> 1] = pkrtz(x00, x01);
        }
    }

    ps[wid][0][lane] = a0;
    ps[wid][1][lane] = a1;
    ps[wid][2][lane] = a2;
    #pragma unroll
    for (int j = 0; j < 8; ++j)
        bt[lane * 33 + (wid << 3) + j] = pk[j];
    __syncthreads();

    if (tid < 192) {
        int k = tid >> 6, ll = tid & 63;
        float s = b_off[2 * k];
        #pragma unroll
        for (int w4 = 0; w4 < 4; ++w4) s += ps[w4][k][ll];
        float g = fminf(fmaxf((float)(l0 + ll + 1) + s, 0.f), 8193.f);
        gbuf[((size_t)n * LEN + l0 + ll) * 3 + k] = g;
    }

    {
        int row = tid >> 2, grp = tid & 3;
        const unsigned int* src = &bt[row * 33 + (grp << 3)];
        uint4 u0, u1;
        u0.x = src[0]; u0.y = src[1]; u0.z = src[2]; u0.w = src[3];
        u1.x = src[4]; u1.y = src[5]; u1.z = src[6]; u1.w = src[7];
        size_t base = ((size_t)n * LP2 + 1 + l0 + row) * 32 + (grp << 3);
        *(uint4*)&xt32[base]     = u0;
        *(uint4*)&xt32[base + 4] = u1;
    }
    if (t == 0   && tid < 32) xt32[((size_t)n * LP2) * 32 + tid] = 0u;
    if (t == 127 && tid < 64) xt32[((size_t)n * LP2 + 8193 + (tid >> 5)) * 32 + (tid & 31)] = 0u;
}

// ---------------- Kernel D8 (frozen, R13 best): LDS-staged B + f16 packed-lerp + f16 MFMA ----------------
__global__ __launch_bounds__(256) void dconv8_kernel(
    const unsigned short* __restrict__ xt16, const unsigned short* __restrict__ wtf,
    const float* __restrict__ bias, const float* __restrict__ gbuf,
    float* __restrict__ out)
{
    __shared__ unsigned short Bl[MSZ * 64];    // 24 KB
    __shared__ __align__(16) int2 meta[MSZ];
    int tid = threadIdx.x;

    // bijective XCD swizzle: XCD x = wg&7 serves only n in {2x, 2x+1}
    int wg  = blockIdx.x;
    int xcd = wg & 7;
    int tt  = wg >> 3;
    int n   = (xcd << 1) | (tt >> 7);
    int p   = tt & 127;

    if (tid < MSZ) {
        int k = tid >> 6, r = tid & 63;
        int l = (r << 7) | p;
        float g  = gbuf[((size_t)n * LEN + l) * 3 + k];
        float fl = floorf(g);
        meta[tid] = make_int2((int)fl, __float_as_int(g - fl));
    }
    __syncthreads();

    const unsigned short* xb = xt16 + (size_t)n * LP2 * 64;

    // stage B: task = (m, 8-channel chunk); single barrier, all loads overlapped
    #pragma unroll
    for (int j = 0; j < 6; ++j) {
        int task = tid + (j << 8);       // 0..1535
        int m  = task >> 3;
        int ch = task & 7;
        int2 mv = meta[m];
        float a = __int_as_float(mv.y);
        _Float16 ah = (_Float16)a;
        f16x2 a2; a2[0] = ah; a2[1] = ah;
        const unsigned short* rl = xb + ((size_t)(unsigned)mv.x << 6) + (ch << 3);
        uint4 vl4 = *(const uint4*)rl;
        uint4 vr4 = *(const uint4*)(rl + 64);
        const f16x2* vlh = (const f16x2*)&vl4;
        const f16x2* vrh = (const f16x2*)&vr4;
        uint4 ov;
        unsigned int* ovp = (unsigned int*)&ov;
        #pragma unroll
        for (int q = 0; q < 4; ++q) {
            f16x2 r = vlh[q] + a2 * (vrh[q] - vlh[q]);   // v_pk_{sub,fma}_f16
            ovp[q] = __builtin_bit_cast(unsigned int, r);
        }
        int dst = (m << 6) + ((ch << 3) ^ (((m >> 3) & 3) << 4));
        *(uint4*)&Bl[dst] = ov;
    }
    __syncthreads();

    int lane = tid & 63;
    int ct   = tid >> 6;
    int g4   = lane >> 4;
    int c    = (ct << 4) | (lane & 15);

    f32x4 acc[4] = {};

    #pragma unroll
    for (int ks = 0; ks < 6; ++ks) {
        int mb = ks * 32 + (g4 << 3);
        int cx = c ^ ((((unsigned)(mb >> 3)) & 3) << 4);
        f16x8 afrag;
        #pragma unroll
        for (int s = 0; s < 8; ++s)
            afrag[s] = __builtin_bit_cast(_Float16, Bl[((mb + s) << 6) + cx]);

        #pragma unroll
        for (int ot = 0; ot < 4; ++ot) {
            f16x8 bfrag = *(const f16x8*)(wtf + ((size_t)(((ot * 6 + ks) << 6) + lane) << 3));
            acc[ot] = __builtin_amdgcn_mfma_f32_16x16x32_f16(afrag, bfrag, acc[ot], 0, 0, 0);
        }
    }

    // D layout: col(o) = lane&15, row(c-block) = (lane>>4)*4 + reg
    int q0 = (p << 6) + ct * 16 + g4 * 4;
    #pragma unroll
    for (int ot = 0; ot < 4; ++ot) {
        int o = ot * 16 + (lane & 15);
        float bb = bias[o];
        float4 r4;
        r4.x = acc[ot][0] + bb;
        r4.y = acc[ot][1] + bb;
        r4.z = acc[ot][2] + bb;
        r4.w = acc[ot][3] + bb;
        *(float4*)&out[((size_t)n * COUT + o) * LEN + q0] = r4;
    }
}

extern "C" void kernel_launch(void* const* d_in, const int* in_sizes, int n_in,
                              void* d_out, int out_size, void* d_ws, size_t ws_size,
                              hipStream_t stream) {
    const float* x     = (const float*)d_in[0];
    const float* w_off = (const float*)d_in[1];
    const float* b_off = (const float*)d_in[2];
    const float* w     = (const float*)d_in[3];
    const float* b     = (const float*)d_in[4];
    float* out = (float*)d_out;

    const size_t GBUF_B = (size_t)NB * LEN * 3 * sizeof(float);     // 6,291,456
    const size_t WTF_B  = (size_t)MSZ * COUT * sizeof(short);       // 24,576
    float*          gbuf = (float*)d_ws;
    unsigned short* wtf  = (unsigned short*)((char*)d_ws + GBUF_B);
    unsigned int*   xt32 = (unsigned int*)((char*)d_ws + GBUF_B + WTF_B);
    unsigned short* xt16 = (unsigned short*)xt32;

    prep5_kernel<<<NB * 128 + 24, 256, 0, stream>>>(x, w_off, b_off, w, gbuf, xt32, wtf);
    dconv8_kernel<<<NB * 128, 256, 0, stream>>>(xt16, wtf, b, gbuf, out);
}

// Round 17
// 33.516 us; speedup vs baseline: 5.2732x; 1.0007x over previous
//
#include <hip/hip_runtime.h>
#include <hip/hip_bf16.h>
#include <math.h>

#define NB   16
#define CIN  64
#define LEN  8192
#define LP2  8195     // rows: 0 = left pad(0), 1..8192 = x, 8193/8194 = right pad(0)
#define COUT 64
#define MSZ  192

typedef float    f32x4  __attribute__((ext_vector_type(4)));
typedef float    f32x4u __attribute__((ext_vector_type(4), aligned(4)));
typedef _Float16 f16x8  __attribute__((ext_vector_type(8)));
typedef _Float16 f16x2  __attribute__((ext_vector_type(2)));

static __device__ inline unsigned int pkrtz(float lo, float hi) {
    return __builtin_bit_cast(unsigned int, __builtin_amdgcn_cvt_pkrtz(lo, hi)); // low16=lo, high16=hi
}

// ---------------- Kernel P5 (frozen, R16): prep + float4 tap loads ----------------
__global__ __launch_bounds__(256) void prep5_kernel(
    const float* __restrict__ x, const float* __restrict__ w_off,
    const float* __restrict__ b_off, const float* __restrict__ w,
    float* __restrict__ gbuf, unsigned int* __restrict__ xt32,
    unsigned short* __restrict__ wtf)
{
    int bid = blockIdx.x;
    int tid = threadIdx.x;

    if (bid >= NB * 128) {
        // ---- wfrag: b = ot*6 + ks ----
        int b = bid - NB * 128;          // 0..23
        int ot = b / 6, ks = b - ot * 6;
        #pragma unroll
        for (int h = 0; h < 2; ++h) {
            int t2 = tid + h * 256;
            int lq = t2 >> 3, s = t2 & 7;
            int o = ot * 16 + (lq & 15);
            int m = ks * 32 + (lq >> 4) * 8 + s;
            _Float16 hv = (_Float16)w[o * MSZ + m];
            wtf[b * 512 + t2] = __builtin_bit_cast(unsigned short, hv);
        }
        return;
    }

    __shared__ float ps[4][3][64];
    __shared__ unsigned int bt[64 * 33];

    int lane = tid & 63;
    int wid  = __builtin_amdgcn_readfirstlane(tid >> 6);
    // XCD-aligned mapping: same bijective swizzle as dconv
    int xcd = bid & 7;
    int tt  = bid >> 3;               // 0..255
    int n   = (xcd << 1) | (tt >> 7);
    int t   = tt & 127;
    int l0 = t << 6;
    int l  = l0 + lane;
    const float* xn = x + (size_t)n * (CIN * LEN);

    float a0 = 0.f, a1 = 0.f, a2 = 0.f;
    unsigned int pk[8];

    if (t != 0 && t != 127) {
        #pragma unroll
        for (int ci = 0; ci < 16; ci += 2) {
            int c0 = (wid << 4) | ci;
            const float* xc0 = xn + (size_t)c0 * LEN;
            const float* xc1 = xc0 + LEN;
            f32x4u v0 = *(const f32x4u*)&xc0[l - 1];
            f32x4u v1 = *(const f32x4u*)&xc1[l - 1];
            const float* wa = w_off + (size_t)c0 * 3;
            const float* wb = wa + 384;
            const float* wc = wa + 768;
            a0 = fmaf(wa[0], v0.x, a0); a0 = fmaf(wa[1], v0.y, a0); a0 = fmaf(wa[2], v0.z, a0);
            a0 = fmaf(wa[3], v1.x, a0); a0 = fmaf(wa[4], v1.y, a0); a0 = fmaf(wa[5], v1.z, a0);
            a1 = fmaf(wb[0], v0.x, a1); a1 = fmaf(wb[1], v0.y, a1); a1 = fmaf(wb[2], v0.z, a1);
            a1 = fmaf(wb[3], v1.x, a1); a1 = fmaf(wb[4], v1.y, a1); a1 = fmaf(wb[5], v1.z, a1);
            a2 = fmaf(wc[0], v0.x, a2); a2 = fmaf(wc[1], v0.y, a2); a2 = fmaf(wc[2], v0.z, a2);
            a2 = fmaf(wc[3], v1.x, a2); a2 = fmaf(wc[4], v1.y, a2); a2 = fmaf(wc[5], v1.z, a2);
            pk[ci >> 1] = pkrtz(v0.y, v1.y);
        }
    } else {
        bool okm = (l >= 1);
        bool okp = (l < LEN - 1);
        #pragma unroll
        for (int ci = 0; ci < 16; ci += 2) {
            int c0 = (wid << 4) | ci;
            const float* xc0 = xn + (size_t)c0 * LEN;
            const float* xc1 = xc0 + LEN;
            float xm0 = okm ? xc0[l - 1] : 0.f;
            float x00 = xc0[l];
            float xp0 = okp ? xc0[l + 1] : 0.f;
            float xm1 = okm ? xc1[l - 1] : 0.f;
            float x01 = xc1[l];
            float xp1 = okp ? xc1[l + 1] : 0.f;
            const float* wa = w_off + (size_t)c0 * 3;
            const float* wb = wa + 384;
            const float* wc = wa + 768;
            a0 = fmaf(wa[0], xm0, a0); a0 = fmaf(wa[1], x00, a0); a0 = fmaf(wa[2], xp0, a0);
            a0 = fmaf(wa[3], xm1, a0); a0 = fmaf(wa[4], x01, a0); a0 = fmaf(wa[5], xp1, a0);
            a1 = fmaf(wb[0], xm0, a1); a1 = fmaf(wb[1], x00, a1); a1 = fmaf(wb[2], xp0, a1);
            a1 = fmaf(wb[3], xm1, a1); a1 = fmaf(wb[4], x01, a1); a1 = fmaf(wb[5], xp1, a1);
            a2 = fmaf(wc[0], xm0, a2); a2 = fmaf(wc[1], x00, a2); a2 = fmaf(wc[2], xp0, a2);
            a2 = fmaf(wc[3], xm1, a2); a2 = fmaf(wc[4], x01, a2); a2 = fmaf(wc[5], xp1, a2);
            pk[ci >> 1] = pkrtz(x00, x01);
        }
    }

    ps[wid][0][lane] = a0;
    ps[wid][1][lane] = a1;
    ps[wid][2][lane] = a2;
    #pragma unroll
    for (int j = 0; j < 8; ++j)
        bt[lane * 33 + (wid << 3) + j] = pk[j];
    __syncthreads();

    if (tid < 192) {
        int k = tid >> 6, ll = tid & 63;
        float s = b_off[2 * k];
        #pragma unroll
        for (int w4 = 0; w4 < 4; ++w4) s += ps[w4][k][ll];
        float g = fminf(fmaxf((float)(l0 + ll + 1) + s, 0.f), 8193.f);
        gbuf[((size_t)n * LEN + l0 + ll) * 3 + k] = g;
    }

    {
        int row = tid >> 2, grp = tid & 3;
        const unsigned int* src = &bt[row * 33 + (grp << 3)];
        uint4 u0, u1;
        u0.x = src[0]; u0.y = src[1]; u0.z = src[2]; u0.w = src[3];
        u1.x = src[4]; u1.y = src[5]; u1.z = src[6]; u1.w = src[7];
        size_t base = ((size_t)n * LP2 + 1 + l0 + row) * 32 + (grp << 3);
        *(uint4*)&xt32[base]     = u0;
        *(uint4*)&xt32[base + 4] = u1;
    }
    if (t == 0   && tid < 32) xt32[((size_t)n * LP2) * 32 + tid] = 0u;
    if (t == 127 && tid < 64) xt32[((size_t)n * LP2 + 8193 + (tid >> 5)) * 32 + (tid & 31)] = 0u;
}

// ---------------- Kernel D10: dconv8 + LOAD-ALL/LERP-ALL staging (1 round-trip, not 6) ----------------
__global__ __launch_bounds__(256) void dconv10_kernel(
    const unsigned short* __restrict__ xt16, const unsigned short* __restrict__ wtf,
    const float* __restrict__ bias, const float* __restrict__ gbuf,
    float* __restrict__ out)
{
    __shared__ unsigned short Bl[MSZ * 64];    // 24 KB
    __shared__ __align__(16) int2 meta[MSZ];
    int tid = threadIdx.x;

    // bijective XCD swizzle: XCD x = wg&7 serves only n in {2x, 2x+1}
    int wg  = blockIdx.x;
    int xcd = wg & 7;
    int tt  = wg >> 3;
    int n   = (xcd << 1) | (tt >> 7);
    int p   = tt & 127;

    if (tid < MSZ) {
        int k = tid >> 6, r = tid & 63;
        int l = (r << 7) | p;
        float g  = gbuf[((size_t)n * LEN + l) * 3 + k];
        float fl = floorf(g);
        meta[tid] = make_int2((int)fl, __float_as_int(g - fl));
    }
    __syncthreads();

    const unsigned short* xb = xt16 + (size_t)n * LP2 * 64;

    // ---- stage phase A: issue ALL 12 gather pairs before any lerp (1 latency exposure) ----
    uint4 vls[6], vrs[6];
    float as_[6];
    int   dst_[6];
    #pragma unroll
    for (int j = 0; j < 6; ++j) {
        int task = tid + (j << 8);       // 0..1535
        int m  = task >> 3;
        int ch = task & 7;
        int2 mv = meta[m];
        as_[j] = __int_as_float(mv.y);
        const unsigned short* rl = xb + ((size_t)(unsigned)mv.x << 6) + (ch << 3);
        vls[j] = *(const uint4*)rl;
        vrs[j] = *(const uint4*)(rl + 64);
        dst_[j] = (m << 6) + ((ch << 3) ^ (((m >> 3) & 3) << 4));
    }
    // ---- stage phase B: lerp + LDS write ----
    #pragma unroll
    for (int j = 0; j < 6; ++j) {
        _Float16 ah = (_Float16)as_[j];
        f16x2 a2; a2[0] = ah; a2[1] = ah;
        const f16x2* vlh = (const f16x2*)&vls[j];
        const f16x2* vrh = (const f16x2*)&vrs[j];
        uint4 ov;
        unsigned int* ovp = (unsigned int*)&ov;
        #pragma unroll
        for (int q = 0; q < 4; ++q) {
            f16x2 r = vlh[q] + a2 * (vrh[q] - vlh[q]);   // v_pk_{sub,fma}_f16
            ovp[q] = __builtin_bit_cast(unsigned int, r);
        }
        *(uint4*)&Bl[dst_[j]] = ov;
    }
    __syncthreads();

    int lane = tid & 63;
    int ct   = tid >> 6;
    int g4   = lane >> 4;
    int c    = (ct << 4) | (lane & 15);

    f32x4 acc[4] = {};

    #pragma unroll
    for (int ks = 0; ks < 6; ++ks) {
        int mb = ks * 32 + (g4 << 3);
        int cx = c ^ ((((unsigned)(mb >> 3)) & 3) << 4);
        f16x8 afrag;
        #pragma unroll
        for (int s = 0; s < 8; ++s)
            afrag[s] = __builtin_bit_cast(_Float16, Bl[((mb + s) << 6) + cx]);

        #pragma unroll
        for (int ot = 0; ot < 4; ++ot) {
            f16x8 bfrag = *(const f16x8*)(wtf + ((size_t)(((ot * 6 + ks) << 6) + lane) << 3));
            acc[ot] = __builtin_amdgcn_mfma_f32_16x16x32_f16(afrag, bfrag, acc[ot], 0, 0, 0);
        }
    }

    // D layout: col(o) = lane&15, row(c-block) = (lane>>4)*4 + reg
    int q0 = (p << 6) + ct * 16 + g4 * 4;
    #pragma unroll
    for (int ot = 0; ot < 4; ++ot) {
        int o = ot * 16 + (lane & 15);
        float bb = bias[o];
        float4 r4;
        r4.x = acc[ot][0] + bb;
        r4.y = acc[ot][1] + bb;
        r4.z = acc[ot][2] + bb;
        r4.w = acc[ot][3] + bb;
        *(float4*)&out[((size_t)n * COUT + o) * LEN + q0] = r4;
    }
}

extern "C" void kernel_launch(void* const* d_in, const int* in_sizes, int n_in,
                              void* d_out, int out_size, void* d_ws, size_t ws_size,
                              hipStream_t stream) {
    const float* x     = (const float*)d_in[0];
    const float* w_off = (const float*)d_in[1];
    const float* b_off = (const float*)d_in[2];
    const float* w     = (const float*)d_in[3];
    const float* b     = (const float*)d_in[4];
    float* out = (float*)d_out;

    const size_t GBUF_B = (size_t)NB * LEN * 3 * sizeof(float);     // 6,291,456
    const size_t WTF_B  = (size_t)MSZ * COUT * sizeof(short);       // 24,576
    float*          gbuf = (float*)d_ws;
    unsigned short* wtf  = (unsigned short*)((char*)d_ws + GBUF_B);
    unsigned int*   xt32 = (unsigned int*)((char*)d_ws + GBUF_B + WTF_B);
    unsigned short* xt16 = (unsigned short*)xt32;

    prep5_kernel<<<NB * 128 + 24, 256, 0, stream>>>(x, w_off, b_off, w, gbuf, xt32, wtf);
    dconv10_kernel<<<NB * 128, 256, 0, stream>>>(xt16, wtf, b, gbuf, out);
}